// Round 9
// baseline (895.365 us; speedup 1.0000x reference)
//
#include <hip/hip_runtime.h>
#include <hip/hip_fp16.h>
#include <math.h>

#define N_NODES 100000
#define N_EDGES 1600000
#define N_GRAPH 1000
#define IN_C 32
#define EDGE_C 16
#define DESC_C 200
#define HDIM 64
#define LAYERS 3
#define SCAN_B 1024
#define N_SBLK ((N_NODES + SCAN_B - 1) / SCAN_B)   // 98
#define NTILES (N_NODES / 16)                      // 6250
#define NCH 2                                      // tiles per wave
#define NGROUPS (NTILES / NCH)                     // 3125
#define NBLK ((NGROUPS + 3) / 4)                   // 782

using f16x8 = __attribute__((ext_vector_type(8))) _Float16;
using f32x4 = __attribute__((ext_vector_type(4))) float;

#define MFMA16(a, b, c) __builtin_amdgcn_mfma_f32_16x16x32_f16((a), (b), (c), 0, 0, 0)

// ---------------- helpers ----------------
__device__ __forceinline__ float2 h2f2(unsigned int u) {
    __half2 h = *reinterpret_cast<const __half2*>(&u);
    return __half22float2(h);
}
__device__ __forceinline__ unsigned int f2h2(float a, float b) {
    __half2 h = __floats2half2_rn(a, b);
    return *reinterpret_cast<unsigned int*>(&h);
}
// swizzled LDS index for a 16x64-half tile (G4)
__device__ __forceinline__ int swz(int row, int c) {
    return row * 64 + (c ^ ((row & 7) << 3));
}

// ---------------- weight folding for edge kernel ----------------
__global__ void precompute_kernel(const float* __restrict__ edge_W, const float* __restrict__ edge_b,
                                  const float* __restrict__ emW1, const float* __restrict__ emb1,
                                  float* __restrict__ K3, float* __restrict__ kb3)
{
    int tid = blockIdx.x * blockDim.x + threadIdx.x;
    if (tid < LAYERS * EDGE_C * HDIM) {
        int l = tid / (EDGE_C * HDIM);
        int k = (tid / HDIM) % EDGE_C;
        int o = tid % HDIM;
        const float* W1l = emW1 + l * (2 * HDIM * HDIM) + HDIM * HDIM;
        float acc = 0.f;
        for (int j = 0; j < HDIM; ++j)
            acc = fmaf(edge_W[k * HDIM + j], W1l[j * HDIM + o], acc);
        K3[tid] = acc;
    }
    if (tid < LAYERS * HDIM) {
        int l = tid / HDIM, o = tid % HDIM;
        const float* W1l = emW1 + l * (2 * HDIM * HDIM) + HDIM * HDIM;
        float acc = emb1[tid];
        for (int j = 0; j < HDIM; ++j)
            acc = fmaf(edge_b[j], W1l[j * HDIM + o], acc);
        kb3[tid] = acc;
    }
}

// ---------------- fp16 transposed weight prep: wt[slot][o*K + k] ----------------
__global__ void wtcvt_kernel(const float* __restrict__ node_W, const float* __restrict__ emW1,
                             const float* __restrict__ emW2, const float* __restrict__ umW1,
                             const float* __restrict__ umW2, _Float16* __restrict__ wt)
{
    int tid = blockIdx.x * blockDim.x + threadIdx.x;
    if (tid >= 16 * 4096) return;
    int slot = tid >> 12, idx = tid & 4095;
    if (slot == 0) {
        if (idx >= 2048) return;
        int o = idx >> 5, k = idx & 31;
        wt[idx] = (_Float16)node_W[k * HDIM + o];
        return;
    }
    int s = slot - 1, lay = s / 5, m = s % 5;
    int o = idx >> 6, k = idx & 63;
    float v;
    if (m == 0)      v = emW1[lay * 2 * HDIM * HDIM + k * HDIM + o];
    else if (m == 1) v = emW2[lay * HDIM * HDIM + k * HDIM + o];
    else if (m == 2) v = umW1[lay * 2 * HDIM * HDIM + k * HDIM + o];
    else if (m == 3) v = umW1[lay * 2 * HDIM * HDIM + (HDIM + k) * HDIM + o];
    else             v = umW2[lay * HDIM * HDIM + k * HDIM + o];
    wt[slot * 4096 + idx] = (_Float16)v;
}

// ---------------- CSR build ----------------
__global__ void deg_kernel(const int* __restrict__ ei, int* __restrict__ deg)
{
    int e = blockIdx.x * blockDim.x + threadIdx.x;
    if (e < N_EDGES) atomicAdd(&deg[ei[N_EDGES + e]], 1);
}

__global__ void cnt_kernel(const int* __restrict__ batch, int* __restrict__ cnt)
{
    int n = blockIdx.x * blockDim.x + threadIdx.x;
    if (n < N_NODES) atomicAdd(&cnt[batch[n]], 1);
}

__global__ void scanA_kernel(const int* __restrict__ in, int* __restrict__ out, int* __restrict__ bsum)
{
    __shared__ int s[SCAN_B];
    int gid = blockIdx.x * SCAN_B + threadIdx.x;
    int v = (gid < N_NODES) ? in[gid] : 0;
    s[threadIdx.x] = v;
    __syncthreads();
    for (int off = 1; off < SCAN_B; off <<= 1) {
        int t = (threadIdx.x >= off) ? s[threadIdx.x - off] : 0;
        __syncthreads();
        s[threadIdx.x] += t;
        __syncthreads();
    }
    if (gid < N_NODES) out[gid] = s[threadIdx.x] - v;
    if (threadIdx.x == SCAN_B - 1) bsum[blockIdx.x] = s[SCAN_B - 1];
}

__global__ void scan1b_kernel(const int* __restrict__ in, int n, int* __restrict__ out)
{
    __shared__ int s[SCAN_B];
    int v = (threadIdx.x < n) ? in[threadIdx.x] : 0;
    s[threadIdx.x] = v;
    __syncthreads();
    for (int off = 1; off < SCAN_B; off <<= 1) {
        int t = (threadIdx.x >= off) ? s[threadIdx.x - off] : 0;
        __syncthreads();
        s[threadIdx.x] += t;
        __syncthreads();
    }
    if (threadIdx.x < n) out[threadIdx.x] = s[threadIdx.x] - v;
    if (threadIdx.x == 0) out[n] = s[SCAN_B - 1];
}

__global__ void scanC_kernel(int* __restrict__ rowptr, const int* __restrict__ bscan,
                             int* __restrict__ cursor)
{
    int gid = blockIdx.x * SCAN_B + threadIdx.x;
    if (gid < N_NODES) {
        int r = rowptr[gid] + bscan[blockIdx.x];
        rowptr[gid] = r;
        cursor[gid] = r;
    }
    if (gid == 0) rowptr[N_NODES] = N_EDGES;
}

// scatter ONE int2 per edge (halves dirty-line count vs two 4B arrays)
__global__ void fill_kernel(const int* __restrict__ ei, int* __restrict__ cursor,
                            int2* __restrict__ srcE)
{
    int e = blockIdx.x * blockDim.x + threadIdx.x;
    if (e < N_EDGES) {
        int src = ei[e];
        int dst = ei[N_EDGES + e];
        int pos = atomicAdd(&cursor[dst], 1);
        srcE[pos] = make_int2(src, e);
    }
}

// streaming fp32->fp16 of edge_attr in ORIGINAL order
__global__ void cvt16_kernel(const float* __restrict__ ea, uint4* __restrict__ eaPh16)
{
    int e = blockIdx.x * blockDim.x + threadIdx.x;
    if (e < N_EDGES) {
        const float4* er = reinterpret_cast<const float4*>(ea + (size_t)e * EDGE_C);
        float4 f0 = er[0], f1 = er[1], f2 = er[2], f3 = er[3];
        uint4 u0, u1;
        u0.x = f2h2(f0.x, f0.y);  u0.y = f2h2(f0.z, f0.w);
        u0.z = f2h2(f1.x, f1.y);  u0.w = f2h2(f1.z, f1.w);
        u1.x = f2h2(f2.x, f2.y);  u1.y = f2h2(f2.z, f2.w);
        u1.z = f2h2(f3.x, f3.y);  u1.w = f2h2(f3.z, f3.w);
        eaPh16[2 * (size_t)e]     = u0;
        eaPh16[2 * (size_t)e + 1] = u1;
    }
}

// permute fp16 edge_attr into CSR order (32B gathers from LLC-resident array, streaming writes)
__global__ void perm_kernel(const int2* __restrict__ srcE, const uint4* __restrict__ eaPh16,
                            uint4* __restrict__ eaPh)
{
    int pos = blockIdx.x * blockDim.x + threadIdx.x;
    if (pos < N_EDGES) {
        int e = srcE[pos].y;
        eaPh[2 * (size_t)pos]     = eaPh16[2 * (size_t)e];
        eaPh[2 * (size_t)pos + 1] = eaPh16[2 * (size_t)e + 1];
    }
}

// ---------------- MFMA embed ----------------
__global__ __launch_bounds__(256)
void embed_mfma_kernel(const float* __restrict__ x, const _Float16* __restrict__ wNt,
                       const float* __restrict__ node_b, const _Float16* __restrict__ wW1,
                       _Float16* __restrict__ hOut, _Float16* __restrict__ hWhOut)
{
    __shared__ _Float16 sb[4][NCH][16 * 64];
    int l = threadIdx.x & 63, w = threadIdx.x >> 6;
    int gid = blockIdx.x * 4 + w;
    if (gid >= NGROUPS) return;
    int lr = l & 15, lg = l >> 4;
    float nbv[4];
    #pragma unroll
    for (int ot = 0; ot < 4; ++ot) nbv[ot] = node_b[ot * 16 + lr];
    f16x8 bN[4];
    #pragma unroll
    for (int ot = 0; ot < 4; ++ot)
        bN[ot] = *(const f16x8*)&wNt[(ot * 16 + lr) * 32 + lg * 8];
    f16x8 bH[8];
    #pragma unroll
    for (int ot = 0; ot < 4; ++ot)
        #pragma unroll
        for (int kt = 0; kt < 2; ++kt)
            bH[ot * 2 + kt] = *(const f16x8*)&wW1[(ot * 16 + lr) * 64 + kt * 32 + lg * 8];

    for (int ti = 0; ti < NCH; ++ti) {
        int nb = (gid * NCH + ti) * 16;
        const float* xs = x + (size_t)(nb + lr) * IN_C + lg * 8;
        float4 x0 = *(const float4*)xs;
        float4 x1 = *(const float4*)(xs + 4);
        f16x8 a;
        a[0] = (_Float16)x0.x; a[1] = (_Float16)x0.y; a[2] = (_Float16)x0.z; a[3] = (_Float16)x0.w;
        a[4] = (_Float16)x1.x; a[5] = (_Float16)x1.y; a[6] = (_Float16)x1.z; a[7] = (_Float16)x1.w;
        #pragma unroll
        for (int ot = 0; ot < 4; ++ot) {
            f32x4 D;
            #pragma unroll
            for (int r = 0; r < 4; ++r) D[r] = nbv[ot];
            D = MFMA16(a, bN[ot], D);
            #pragma unroll
            for (int r = 0; r < 4; ++r) {
                int row = lg * 4 + r;
                sb[w][ti][swz(row, ot * 16 + lr)] = (_Float16)D[r];
            }
        }
        #pragma unroll
        for (int i = 0; i < 2; ++i) {
            int s = i * 64 + l, r = s >> 3, j = s & 7;
            f16x8 v = *(const f16x8*)&sb[w][ti][swz(r, j * 8)];
            *(f16x8*)&hOut[(size_t)nb * 64 + s * 8] = v;
        }
        f16x8 a0 = *(const f16x8*)&sb[w][ti][swz(lr, lg * 8)];
        f16x8 a1 = *(const f16x8*)&sb[w][ti][swz(lr, 32 + lg * 8)];
        #pragma unroll
        for (int ot = 0; ot < 4; ++ot) {
            f32x4 D;
            #pragma unroll
            for (int r = 0; r < 4; ++r) D[r] = 0.f;
            D = MFMA16(a0, bH[ot * 2 + 0], D);
            D = MFMA16(a1, bH[ot * 2 + 1], D);
            #pragma unroll
            for (int r = 0; r < 4; ++r) {
                int row = lg * 4 + r;
                sb[w][ti][swz(row, ot * 16 + lr)] = (_Float16)D[r];
            }
        }
        #pragma unroll
        for (int i = 0; i < 2; ++i) {
            int s = i * 64 + l, r = s >> 3, j = s & 7;
            f16x8 v = *(const f16x8*)&sb[w][ti][swz(r, j * 8)];
            *(f16x8*)&hWhOut[(size_t)nb * 64 + s * 8] = v;
        }
    }
}

// ---------------- MFMA fused node update (per layer) ----------------
__global__ __launch_bounds__(256)
void node_mfma_kernel(const _Float16* __restrict__ hIn, const float* __restrict__ aggZ,
                      const int* __restrict__ deg,
                      const _Float16* __restrict__ wE2, const _Float16* __restrict__ wU1a,
                      const _Float16* __restrict__ wU1b, const _Float16* __restrict__ wU2,
                      const _Float16* __restrict__ wNext,
                      const float* __restrict__ emb2, const float* __restrict__ umb1,
                      const float* __restrict__ umb2,
                      _Float16* __restrict__ hOut, _Float16* __restrict__ hWhOut)
{
    __shared__ _Float16 sb[4][NCH][16 * 64];
    int l = threadIdx.x & 63, w = threadIdx.x >> 6;
    int gid = blockIdx.x * 4 + w;
    if (gid >= NGROUPS) return;
    int lr = l & 15, lg = l >> 4;
    float eb2v[4], ub1v[4], ub2v[4];
    #pragma unroll
    for (int ot = 0; ot < 4; ++ot) {
        eb2v[ot] = emb2[ot * 16 + lr];
        ub1v[ot] = umb1[ot * 16 + lr];
        ub2v[ot] = umb2[ot * 16 + lr];
    }
    int t0 = gid * NCH;

    {   // stage A
        f16x8 bf[8];
        #pragma unroll
        for (int ot = 0; ot < 4; ++ot)
            #pragma unroll
            for (int kt = 0; kt < 2; ++kt)
                bf[ot * 2 + kt] = *(const f16x8*)&wE2[(ot * 16 + lr) * 64 + kt * 32 + lg * 8];
        for (int ti = 0; ti < NCH; ++ti) {
            int nb = (t0 + ti) * 16;
            const float* zs = aggZ + (size_t)(nb + lr) * 64 + lg * 8;
            float4 z0 = *(const float4*)zs;
            float4 z1 = *(const float4*)(zs + 4);
            float4 z2 = *(const float4*)(zs + 32);
            float4 z3 = *(const float4*)(zs + 36);
            f16x8 a0, a1;
            a0[0] = (_Float16)z0.x; a0[1] = (_Float16)z0.y; a0[2] = (_Float16)z0.z; a0[3] = (_Float16)z0.w;
            a0[4] = (_Float16)z1.x; a0[5] = (_Float16)z1.y; a0[6] = (_Float16)z1.z; a0[7] = (_Float16)z1.w;
            a1[0] = (_Float16)z2.x; a1[1] = (_Float16)z2.y; a1[2] = (_Float16)z2.z; a1[3] = (_Float16)z2.w;
            a1[4] = (_Float16)z3.x; a1[5] = (_Float16)z3.y; a1[6] = (_Float16)z3.z; a1[7] = (_Float16)z3.w;
            float dg[4];
            #pragma unroll
            for (int r = 0; r < 4; ++r) dg[r] = (float)deg[nb + lg * 4 + r];
            #pragma unroll
            for (int ot = 0; ot < 4; ++ot) {
                f32x4 D;
                #pragma unroll
                for (int r = 0; r < 4; ++r) D[r] = dg[r] * eb2v[ot];
                D = MFMA16(a0, bf[ot * 2 + 0], D);
                D = MFMA16(a1, bf[ot * 2 + 1], D);
                #pragma unroll
                for (int r = 0; r < 4; ++r) {
                    int row = lg * 4 + r;
                    sb[w][ti][swz(row, ot * 16 + lr)] = (_Float16)D[r];
                }
            }
        }
    }
    {   // stage T
        f16x8 bf[16];
        #pragma unroll
        for (int ot = 0; ot < 4; ++ot)
            #pragma unroll
            for (int kt = 0; kt < 2; ++kt) {
                bf[ot * 2 + kt]     = *(const f16x8*)&wU1a[(ot * 16 + lr) * 64 + kt * 32 + lg * 8];
                bf[8 + ot * 2 + kt] = *(const f16x8*)&wU1b[(ot * 16 + lr) * 64 + kt * 32 + lg * 8];
            }
        for (int ti = 0; ti < NCH; ++ti) {
            int nb = (t0 + ti) * 16;
            const _Float16* hs = hIn + (size_t)(nb + lr) * 64 + lg * 8;
            f16x8 a0 = *(const f16x8*)hs;
            f16x8 a1 = *(const f16x8*)(hs + 32);
            f16x8 c0 = *(const f16x8*)&sb[w][ti][swz(lr, lg * 8)];
            f16x8 c1 = *(const f16x8*)&sb[w][ti][swz(lr, 32 + lg * 8)];
            #pragma unroll
            for (int ot = 0; ot < 4; ++ot) {
                f32x4 D;
                #pragma unroll
                for (int r = 0; r < 4; ++r) D[r] = ub1v[ot];
                D = MFMA16(a0, bf[ot * 2 + 0], D);
                D = MFMA16(a1, bf[ot * 2 + 1], D);
                D = MFMA16(c0, bf[8 + ot * 2 + 0], D);
                D = MFMA16(c1, bf[8 + ot * 2 + 1], D);
                #pragma unroll
                for (int r = 0; r < 4; ++r) {
                    int row = lg * 4 + r;
                    sb[w][ti][swz(row, ot * 16 + lr)] = (_Float16)fmaxf(D[r], 0.f);
                }
            }
        }
    }
    {   // stage h'
        f16x8 bf[8];
        #pragma unroll
        for (int ot = 0; ot < 4; ++ot)
            #pragma unroll
            for (int kt = 0; kt < 2; ++kt)
                bf[ot * 2 + kt] = *(const f16x8*)&wU2[(ot * 16 + lr) * 64 + kt * 32 + lg * 8];
        for (int ti = 0; ti < NCH; ++ti) {
            int nb = (t0 + ti) * 16;
            f16x8 a0 = *(const f16x8*)&sb[w][ti][swz(lr, lg * 8)];
            f16x8 a1 = *(const f16x8*)&sb[w][ti][swz(lr, 32 + lg * 8)];
            #pragma unroll
            for (int ot = 0; ot < 4; ++ot) {
                f32x4 D;
                #pragma unroll
                for (int r = 0; r < 4; ++r) D[r] = ub2v[ot];
                D = MFMA16(a0, bf[ot * 2 + 0], D);
                D = MFMA16(a1, bf[ot * 2 + 1], D);
                #pragma unroll
                for (int r = 0; r < 4; ++r) {
                    int row = lg * 4 + r;
                    sb[w][ti][swz(row, ot * 16 + lr)] = (_Float16)D[r];
                }
            }
            #pragma unroll
            for (int i = 0; i < 2; ++i) {
                int s = i * 64 + l, r = s >> 3, j = s & 7;
                f16x8 v = *(const f16x8*)&sb[w][ti][swz(r, j * 8)];
                *(f16x8*)&hOut[(size_t)nb * 64 + s * 8] = v;
            }
        }
    }
    if (wNext) {   // stage hw
        f16x8 bf[8];
        #pragma unroll
        for (int ot = 0; ot < 4; ++ot)
            #pragma unroll
            for (int kt = 0; kt < 2; ++kt)
                bf[ot * 2 + kt] = *(const f16x8*)&wNext[(ot * 16 + lr) * 64 + kt * 32 + lg * 8];
        for (int ti = 0; ti < NCH; ++ti) {
            int nb = (t0 + ti) * 16;
            f16x8 a0 = *(const f16x8*)&sb[w][ti][swz(lr, lg * 8)];
            f16x8 a1 = *(const f16x8*)&sb[w][ti][swz(lr, 32 + lg * 8)];
            #pragma unroll
            for (int ot = 0; ot < 4; ++ot) {
                f32x4 D;
                #pragma unroll
                for (int r = 0; r < 4; ++r) D[r] = 0.f;
                D = MFMA16(a0, bf[ot * 2 + 0], D);
                D = MFMA16(a1, bf[ot * 2 + 1], D);
                #pragma unroll
                for (int r = 0; r < 4; ++r) {
                    int row = lg * 4 + r;
                    sb[w][ti][swz(row, ot * 16 + lr)] = (_Float16)D[r];
                }
            }
            #pragma unroll
            for (int i = 0; i < 2; ++i) {
                int s = i * 64 + l, r = s >> 3, j = s & 7;
                f16x8 v = *(const f16x8*)&sb[w][ti][swz(r, j * 8)];
                *(f16x8*)&hWhOut[(size_t)nb * 64 + s * 8] = v;
            }
        }
    }
}

// ---------------- edge aggregation (CSR gather, fp16, no atomics) ----------------
__device__ __forceinline__ float edge_term(float hv, uint4 a, uint4 b,
                                           const float* Kc, float kbo)
{
    float z = hv + kbo;
    float2 t;
    t = h2f2(a.x); z = fmaf(t.x, Kc[0], z);  z = fmaf(t.y, Kc[1], z);
    t = h2f2(a.y); z = fmaf(t.x, Kc[2], z);  z = fmaf(t.y, Kc[3], z);
    t = h2f2(a.z); z = fmaf(t.x, Kc[4], z);  z = fmaf(t.y, Kc[5], z);
    t = h2f2(a.w); z = fmaf(t.x, Kc[6], z);  z = fmaf(t.y, Kc[7], z);
    t = h2f2(b.x); z = fmaf(t.x, Kc[8], z);  z = fmaf(t.y, Kc[9], z);
    t = h2f2(b.y); z = fmaf(t.x, Kc[10], z); z = fmaf(t.y, Kc[11], z);
    t = h2f2(b.z); z = fmaf(t.x, Kc[12], z); z = fmaf(t.y, Kc[13], z);
    t = h2f2(b.w); z = fmaf(t.x, Kc[14], z); z = fmaf(t.y, Kc[15], z);
    return fmaxf(z, 0.f);
}

__global__ void edge_agg_kernel(const int* __restrict__ rowptr, const int2* __restrict__ srcE,
                                const uint4* __restrict__ eaPh, const __half* __restrict__ hWh,
                                const float* __restrict__ K, const float* __restrict__ kb,
                                float* __restrict__ aggZ)
{
    int o = threadIdx.x & 63;
    int w = threadIdx.x >> 6;
    float Kc[EDGE_C];
    #pragma unroll
    for (int k = 0; k < EDGE_C; ++k) Kc[k] = K[k * HDIM + o];
    float kbo = kb[o];
    int wid = blockIdx.x * 4 + w, nw = gridDim.x * 4;
    for (int n = wid; n < N_NODES; n += nw) {
        int beg = __builtin_amdgcn_readfirstlane(rowptr[n]);
        int end = __builtin_amdgcn_readfirstlane(rowptr[n + 1]);
        float acc = 0.f;
        int p = beg;
        for (; p + 3 < end; p += 4) {
            int s0 = srcE[p].x, s1 = srcE[p + 1].x, s2 = srcE[p + 2].x, s3 = srcE[p + 3].x;
            uint4 a0 = eaPh[2 * (size_t)p + 0], b0 = eaPh[2 * (size_t)p + 1];
            uint4 a1 = eaPh[2 * (size_t)p + 2], b1 = eaPh[2 * (size_t)p + 3];
            uint4 a2 = eaPh[2 * (size_t)p + 4], b2 = eaPh[2 * (size_t)p + 5];
            uint4 a3 = eaPh[2 * (size_t)p + 6], b3 = eaPh[2 * (size_t)p + 7];
            float h0 = __half2float(hWh[(size_t)s0 * HDIM + o]);
            float h1 = __half2float(hWh[(size_t)s1 * HDIM + o]);
            float h2 = __half2float(hWh[(size_t)s2 * HDIM + o]);
            float h3 = __half2float(hWh[(size_t)s3 * HDIM + o]);
            acc += edge_term(h0, a0, b0, Kc, kbo);
            acc += edge_term(h1, a1, b1, Kc, kbo);
            acc += edge_term(h2, a2, b2, Kc, kbo);
            acc += edge_term(h3, a3, b3, Kc, kbo);
        }
        for (; p < end; ++p) {
            int s = srcE[p].x;
            uint4 a = eaPh[2 * (size_t)p], b = eaPh[2 * (size_t)p + 1];
            float hv = __half2float(hWh[(size_t)s * HDIM + o]);
            acc += edge_term(hv, a, b, Kc, kbo);
        }
        aggZ[(size_t)n * HDIM + o] = acc;
    }
}

// ---------------- pooling / readout ----------------
__global__ void pool_graph_kernel(const _Float16* __restrict__ h, const int* __restrict__ gptr,
                                  float* __restrict__ pooled)
{
    int o = threadIdx.x & 63;
    int w = threadIdx.x >> 6;
    int wid = blockIdx.x * 4 + w, nw = gridDim.x * 4;
    for (int g = wid; g < N_GRAPH; g += nw) {
        int beg = gptr[g], end = gptr[g + 1];
        float acc = 0.f;
        for (int n = beg; n < end; ++n) acc += (float)h[(size_t)n * HDIM + o];
        pooled[g * HDIM + o] = acc;
    }
}

__global__ void readout_kernel(const float* __restrict__ pooled, const int* __restrict__ gptr,
                               const float* __restrict__ desc,
                               const float* __restrict__ W1, const float* __restrict__ b1,
                               const float* __restrict__ W2, const float* __restrict__ b2,
                               float* __restrict__ out)
{
    __shared__ float r[HDIM + DESC_C];
    __shared__ float red[128];
    int g = blockIdx.x;
    int t = threadIdx.x;
    float c = fmaxf((float)(gptr[g + 1] - gptr[g]), 1.f);
    for (int i = t; i < HDIM; i += 128) r[i] = pooled[g * HDIM + i] / c;
    for (int i = t; i < DESC_C; i += 128) r[HDIM + i] = desc[(size_t)g * DESC_C + i];
    __syncthreads();
    float acc = b1[t];
    for (int k = 0; k < HDIM + DESC_C; ++k) acc = fmaf(r[k], W1[k * 128 + t], acc);
    acc = fmaxf(acc, 0.f) * W2[t];
    red[t] = acc;
    __syncthreads();
    for (int s = 64; s > 0; s >>= 1) {
        if (t < s) red[t] += red[t + s];
        __syncthreads();
    }
    if (t == 0) out[g] = 1.f / (1.f + expf(-(red[0] + b2[0])));
}

extern "C" void kernel_launch(void* const* d_in, const int* in_sizes, int n_in,
                              void* d_out, int out_size, void* d_ws, size_t ws_size,
                              hipStream_t stream)
{
    const float* x         = (const float*)d_in[0];
    const int*   ei        = (const int*)d_in[1];
    const float* edge_attr = (const float*)d_in[2];
    const int*   batch     = (const int*)d_in[3];
    const float* desc      = (const float*)d_in[4];
    const float* node_W    = (const float*)d_in[5];
    const float* node_b    = (const float*)d_in[6];
    const float* edge_W    = (const float*)d_in[7];
    const float* edge_b    = (const float*)d_in[8];
    const float* emW1      = (const float*)d_in[9];
    const float* emb1      = (const float*)d_in[10];
    const float* emW2      = (const float*)d_in[11];
    const float* emb2      = (const float*)d_in[12];
    const float* umW1      = (const float*)d_in[13];
    const float* umb1      = (const float*)d_in[14];
    const float* umW2      = (const float*)d_in[15];
    const float* umb2      = (const float*)d_in[16];
    const float* ro_W1     = (const float*)d_in[17];
    const float* ro_b1     = (const float*)d_in[18];
    const float* ro_W2     = (const float*)d_in[19];
    const float* ro_b2     = (const float*)d_in[20];

    size_t NH = (size_t)N_NODES * HDIM;
    char* base = (char*)d_ws;
    _Float16* hH   = (_Float16*)base;                    // 12.8 MB
    _Float16* hWh  = hH + NH;                            // 12.8 MB
    float* aggZ    = (float*)(base + NH * 4);            // 25.6 MB
    // eaPh16orig (51.2 MB) aliases [hH, hWh, aggZ] — consumed by perm BEFORE embed writes hH/hWh
    uint4* eaPh16  = (uint4*)base;
    uint4* eaPh    = (uint4*)(base + NH * 8);            // 51.2 MB, CSR-ordered fp16 ea
    int2* srcE     = (int2*)(eaPh + 2 * (size_t)N_EDGES);// 12.8 MB
    int* deg       = (int*)(srcE + N_EDGES);
    int* rowptr    = deg + N_NODES;
    int* cursor    = rowptr + N_NODES + 1;
    int* cnt       = cursor + N_NODES;
    int* gptr      = cnt + N_GRAPH;
    int* bsum      = gptr + N_GRAPH + 1;
    int* bscan     = bsum + N_SBLK;
    float* K3      = (float*)(bscan + N_SBLK + 1);
    float* kb3     = K3 + LAYERS * EDGE_C * HDIM;
    float* pooled  = kb3 + LAYERS * HDIM;
    _Float16* wt   = (_Float16*)(pooled + N_GRAPH * HDIM);

    hipMemsetAsync(deg, 0, N_NODES * sizeof(int), stream);
    hipMemsetAsync(cnt, 0, N_GRAPH * sizeof(int), stream);

    wtcvt_kernel<<<256, 256, 0, stream>>>(node_W, emW1, emW2, umW1, umW2, wt);
    precompute_kernel<<<12, 256, 0, stream>>>(edge_W, edge_b, emW1, emb1, K3, kb3);
    deg_kernel<<<(N_EDGES + 255) / 256, 256, 0, stream>>>(ei, deg);
    cnt_kernel<<<(N_NODES + 255) / 256, 256, 0, stream>>>(batch, cnt);
    cvt16_kernel<<<(N_EDGES + 255) / 256, 256, 0, stream>>>(edge_attr, eaPh16);

    // CSR build
    scanA_kernel<<<N_SBLK, SCAN_B, 0, stream>>>(deg, rowptr, bsum);
    scan1b_kernel<<<1, SCAN_B, 0, stream>>>(bsum, N_SBLK, bscan);
    scanC_kernel<<<N_SBLK, SCAN_B, 0, stream>>>(rowptr, bscan, cursor);
    fill_kernel<<<(N_EDGES + 255) / 256, 256, 0, stream>>>(ei, cursor, srcE);

    perm_kernel<<<(N_EDGES + 255) / 256, 256, 0, stream>>>(srcE, eaPh16, eaPh);
    scan1b_kernel<<<1, SCAN_B, 0, stream>>>(cnt, N_GRAPH, gptr);

    const _Float16* wNt = wt;
    embed_mfma_kernel<<<NBLK, 256, 0, stream>>>(x, wNt, node_b,
                                                wt + (size_t)(1 + 0 * 5 + 0) * 4096, hH, hWh);

    for (int l = 0; l < LAYERS; ++l) {
        edge_agg_kernel<<<4096, 256, 0, stream>>>(rowptr, srcE, eaPh, (const __half*)hWh,
                                                  K3 + l * EDGE_C * HDIM, kb3 + l * HDIM, aggZ);
        const _Float16* wE2  = wt + (size_t)(1 + l * 5 + 1) * 4096;
        const _Float16* wU1a = wt + (size_t)(1 + l * 5 + 2) * 4096;
        const _Float16* wU1b = wt + (size_t)(1 + l * 5 + 3) * 4096;
        const _Float16* wU2  = wt + (size_t)(1 + l * 5 + 4) * 4096;
        const _Float16* wNx  = (l + 1 < LAYERS) ? (wt + (size_t)(1 + (l + 1) * 5 + 0) * 4096)
                                                : nullptr;
        node_mfma_kernel<<<NBLK, 256, 0, stream>>>(hH, aggZ, deg, wE2, wU1a, wU1b, wU2, wNx,
                                                   emb2 + l * HDIM, umb1 + l * HDIM,
                                                   umb2 + l * HDIM, hH, hWh);
    }

    pool_graph_kernel<<<256, 256, 0, stream>>>(hH, gptr, pooled);
    readout_kernel<<<N_GRAPH, 128, 0, stream>>>(pooled, gptr, desc, ro_W1, ro_b1, ro_W2, ro_b2,
                                                (float*)d_out);
}

// Round 10
// 680.177 us; speedup vs baseline: 1.3164x; 1.3164x over previous
//
#include <hip/hip_runtime.h>
#include <hip/hip_fp16.h>
#include <math.h>

#define N_NODES 100000
#define N_EDGES 1600000
#define N_GRAPH 1000
#define IN_C 32
#define EDGE_C 16
#define DESC_C 200
#define HDIM 64
#define LAYERS 3
#define NTILES (N_NODES / 16)
#define NCH 2
#define NGROUPS (NTILES / NCH)
#define NBLK ((NGROUPS + 3) / 4)

#define BUCK_SH 8
#define NBUCK ((N_NODES + 255) / 256)   // 391
#define EPB 4096                        // edges per block in binning
#define GRID_A ((N_EDGES + EPB - 1) / EPB)  // 391

using f16x8 = __attribute__((ext_vector_type(8))) _Float16;
using f32x4 = __attribute__((ext_vector_type(4))) float;

#define MFMA16(a, b, c) __builtin_amdgcn_mfma_f32_16x16x32_f16((a), (b), (c), 0, 0, 0)

// ---------------- helpers ----------------
__device__ __forceinline__ float2 h2f2(unsigned int u) {
    __half2 h = *reinterpret_cast<const __half2*>(&u);
    return __half22float2(h);
}
__device__ __forceinline__ unsigned int f2h2(float a, float b) {
    __half2 h = __floats2half2_rn(a, b);
    return *reinterpret_cast<unsigned int*>(&h);
}
__device__ __forceinline__ int swz(int row, int c) {
    return row * 64 + (c ^ ((row & 7) << 3));
}

// ---------------- weight folding for edge kernel ----------------
__global__ void precompute_kernel(const float* __restrict__ edge_W, const float* __restrict__ edge_b,
                                  const float* __restrict__ emW1, const float* __restrict__ emb1,
                                  float* __restrict__ K3, float* __restrict__ kb3)
{
    int tid = blockIdx.x * blockDim.x + threadIdx.x;
    if (tid < LAYERS * EDGE_C * HDIM) {
        int l = tid / (EDGE_C * HDIM);
        int k = (tid / HDIM) % EDGE_C;
        int o = tid % HDIM;
        const float* W1l = emW1 + l * (2 * HDIM * HDIM) + HDIM * HDIM;
        float acc = 0.f;
        for (int j = 0; j < HDIM; ++j)
            acc = fmaf(edge_W[k * HDIM + j], W1l[j * HDIM + o], acc);
        K3[tid] = acc;
    }
    if (tid < LAYERS * HDIM) {
        int l = tid / HDIM, o = tid % HDIM;
        const float* W1l = emW1 + l * (2 * HDIM * HDIM) + HDIM * HDIM;
        float acc = emb1[tid];
        for (int j = 0; j < HDIM; ++j)
            acc = fmaf(edge_b[j], W1l[j * HDIM + o], acc);
        kb3[tid] = acc;
    }
}

// ---------------- fp16 transposed weight prep ----------------
__global__ void wtcvt_kernel(const float* __restrict__ node_W, const float* __restrict__ emW1,
                             const float* __restrict__ emW2, const float* __restrict__ umW1,
                             const float* __restrict__ umW2, _Float16* __restrict__ wt)
{
    int tid = blockIdx.x * blockDim.x + threadIdx.x;
    if (tid >= 16 * 4096) return;
    int slot = tid >> 12, idx = tid & 4095;
    if (slot == 0) {
        if (idx >= 2048) return;
        int o = idx >> 5, k = idx & 31;
        wt[idx] = (_Float16)node_W[k * HDIM + o];
        return;
    }
    int s = slot - 1, lay = s / 5, m = s % 5;
    int o = idx >> 6, k = idx & 63;
    float v;
    if (m == 0)      v = emW1[lay * 2 * HDIM * HDIM + k * HDIM + o];
    else if (m == 1) v = emW2[lay * HDIM * HDIM + k * HDIM + o];
    else if (m == 2) v = umW1[lay * 2 * HDIM * HDIM + k * HDIM + o];
    else if (m == 3) v = umW1[lay * 2 * HDIM * HDIM + (HDIM + k) * HDIM + o];
    else             v = umW2[lay * HDIM * HDIM + k * HDIM + o];
    wt[slot * 4096 + idx] = (_Float16)v;
}

// ---------------- bucket binning: A1 count ----------------
__global__ __launch_bounds__(256)
void binA_count(const int* __restrict__ ei, int* __restrict__ bucketCnt)
{
    __shared__ int hist[NBUCK];
    for (int i = threadIdx.x; i < NBUCK; i += 256) hist[i] = 0;
    __syncthreads();
    int blk = blockIdx.x;
    #pragma unroll
    for (int i = 0; i < 16; ++i) {
        int e = blk * EPB + i * 256 + threadIdx.x;
        if (e < N_EDGES) {
            int dst = ei[N_EDGES + e];
            atomicAdd(&hist[dst >> BUCK_SH], 1);
        }
    }
    __syncthreads();
    for (int i = threadIdx.x; i < NBUCK; i += 256)
        if (hist[i]) atomicAdd(&bucketCnt[i], hist[i]);
}

// ---------------- A2: scan bucket counts (single block) ----------------
__global__ void binA_scan(const int* __restrict__ bucketCnt, int* __restrict__ bucketBase,
                          int* __restrict__ bucketCursor)
{
    __shared__ int s[512];
    int v = (threadIdx.x < NBUCK) ? bucketCnt[threadIdx.x] : 0;
    s[threadIdx.x] = v;
    __syncthreads();
    for (int off = 1; off < 512; off <<= 1) {
        int t = (threadIdx.x >= off) ? s[threadIdx.x - off] : 0;
        __syncthreads();
        s[threadIdx.x] += t;
        __syncthreads();
    }
    if (threadIdx.x < NBUCK) {
        int ex = s[threadIdx.x] - v;
        bucketBase[threadIdx.x] = ex;
        bucketCursor[threadIdx.x] = ex;
    }
}

// ---------------- A3: clustered scatter into bucket-major staging ----------------
// stage[pos].x = src | (dstLocal<<20), stage[pos].y = e
__global__ __launch_bounds__(256)
void binA_scatter(const int* __restrict__ ei, int* __restrict__ bucketCursor,
                  int2* __restrict__ stage)
{
    __shared__ int hist[NBUCK];
    __shared__ int sbase[NBUCK];
    for (int i = threadIdx.x; i < NBUCK; i += 256) hist[i] = 0;
    __syncthreads();
    int blk = blockIdx.x;
    int pk[16], rnk[16], bkt[16];
    #pragma unroll
    for (int i = 0; i < 16; ++i) {
        int e = blk * EPB + i * 256 + threadIdx.x;
        bkt[i] = -1;
        if (e < N_EDGES) {
            int dst = ei[N_EDGES + e];
            int src = ei[e];
            bkt[i] = dst >> BUCK_SH;
            pk[i] = src | ((dst & 255) << 20);
            rnk[i] = atomicAdd(&hist[bkt[i]], 1);
        }
    }
    __syncthreads();
    for (int i = threadIdx.x; i < NBUCK; i += 256)
        if (hist[i]) sbase[i] = atomicAdd(&bucketCursor[i], hist[i]);
    __syncthreads();
    #pragma unroll
    for (int i = 0; i < 16; ++i) {
        if (bkt[i] >= 0) {
            int e = blk * EPB + i * 256 + threadIdx.x;
            stage[sbase[bkt[i]] + rnk[i]] = make_int2(pk[i], e);
        }
    }
}

// ---------------- B: per-bucket CSR finalize (single-CU scatter -> no write amp) ----------------
__global__ __launch_bounds__(256)
void binB_finalize(const int* __restrict__ bucketCnt, const int* __restrict__ bucketBase,
                   const int2* __restrict__ stage, int* __restrict__ rowptr,
                   int* __restrict__ deg, int* __restrict__ srcIdx, int* __restrict__ eIdx)
{
    __shared__ int hist[256];
    __shared__ int s[256];
    __shared__ int cur[256];
    int b = blockIdx.x;
    int base = bucketBase[b], cnt = bucketCnt[b];
    int n0 = b << BUCK_SH;
    int nn = min(256, N_NODES - n0);
    hist[threadIdx.x] = 0;
    __syncthreads();
    for (int j = threadIdx.x; j < cnt; j += 256)
        atomicAdd(&hist[(stage[base + j].x >> 20) & 255], 1);
    __syncthreads();
    int v = hist[threadIdx.x];
    s[threadIdx.x] = v;
    __syncthreads();
    for (int off = 1; off < 256; off <<= 1) {
        int t = (threadIdx.x >= off) ? s[threadIdx.x - off] : 0;
        __syncthreads();
        s[threadIdx.x] += t;
        __syncthreads();
    }
    int ex = s[threadIdx.x] - v;
    if (threadIdx.x < nn) {
        rowptr[n0 + threadIdx.x] = base + ex;
        deg[n0 + threadIdx.x] = v;
    }
    cur[threadIdx.x] = ex;
    if (b == 0 && threadIdx.x == 0) rowptr[N_NODES] = N_EDGES;
    __syncthreads();
    for (int j = threadIdx.x; j < cnt; j += 256) {
        int2 se = stage[base + j];
        int dl = (se.x >> 20) & 255;
        int r = atomicAdd(&cur[dl], 1);
        srcIdx[base + r] = se.x & 0x1FFFF;
        eIdx[base + r] = se.y;
    }
}

// ---------------- perm: gather fp32 edge_attr by CSR order, write fp16 ----------------
__global__ void perm_kernel(const int* __restrict__ eIdx, const float* __restrict__ ea,
                            uint4* __restrict__ eaPh)
{
    int pos = blockIdx.x * blockDim.x + threadIdx.x;
    if (pos < N_EDGES) {
        int e = eIdx[pos];
        const float4* er = reinterpret_cast<const float4*>(ea + (size_t)e * EDGE_C);
        float4 f0 = er[0], f1 = er[1], f2 = er[2], f3 = er[3];
        uint4 u0, u1;
        u0.x = f2h2(f0.x, f0.y);  u0.y = f2h2(f0.z, f0.w);
        u0.z = f2h2(f1.x, f1.y);  u0.w = f2h2(f1.z, f1.w);
        u1.x = f2h2(f2.x, f2.y);  u1.y = f2h2(f2.z, f2.w);
        u1.z = f2h2(f3.x, f3.y);  u1.w = f2h2(f3.z, f3.w);
        eaPh[2 * (size_t)pos]     = u0;
        eaPh[2 * (size_t)pos + 1] = u1;
    }
}

// ---------------- gptr from sorted batch (no atomics) ----------------
__global__ void gptr_kernel(const int* __restrict__ batch, int* __restrict__ gptr)
{
    int n = blockIdx.x * blockDim.x + threadIdx.x;
    if (n < N_NODES) {
        int b = batch[n];
        if (n == 0) {
            for (int g = 0; g <= b; ++g) gptr[g] = 0;
        } else {
            int pb = batch[n - 1];
            for (int g = pb + 1; g <= b; ++g) gptr[g] = n;
        }
        if (n == N_NODES - 1)
            for (int g = b + 1; g <= N_GRAPH; ++g) gptr[g] = N_NODES;
    }
}

// ---------------- MFMA embed ----------------
__global__ __launch_bounds__(256)
void embed_mfma_kernel(const float* __restrict__ x, const _Float16* __restrict__ wNt,
                       const float* __restrict__ node_b, const _Float16* __restrict__ wW1,
                       _Float16* __restrict__ hOut, _Float16* __restrict__ hWhOut)
{
    __shared__ _Float16 sb[4][NCH][16 * 64];
    int l = threadIdx.x & 63, w = threadIdx.x >> 6;
    int gid = blockIdx.x * 4 + w;
    if (gid >= NGROUPS) return;
    int lr = l & 15, lg = l >> 4;
    float nbv[4];
    #pragma unroll
    for (int ot = 0; ot < 4; ++ot) nbv[ot] = node_b[ot * 16 + lr];
    f16x8 bN[4];
    #pragma unroll
    for (int ot = 0; ot < 4; ++ot)
        bN[ot] = *(const f16x8*)&wNt[(ot * 16 + lr) * 32 + lg * 8];
    f16x8 bH[8];
    #pragma unroll
    for (int ot = 0; ot < 4; ++ot)
        #pragma unroll
        for (int kt = 0; kt < 2; ++kt)
            bH[ot * 2 + kt] = *(const f16x8*)&wW1[(ot * 16 + lr) * 64 + kt * 32 + lg * 8];

    for (int ti = 0; ti < NCH; ++ti) {
        int nb = (gid * NCH + ti) * 16;
        const float* xs = x + (size_t)(nb + lr) * IN_C + lg * 8;
        float4 x0 = *(const float4*)xs;
        float4 x1 = *(const float4*)(xs + 4);
        f16x8 a;
        a[0] = (_Float16)x0.x; a[1] = (_Float16)x0.y; a[2] = (_Float16)x0.z; a[3] = (_Float16)x0.w;
        a[4] = (_Float16)x1.x; a[5] = (_Float16)x1.y; a[6] = (_Float16)x1.z; a[7] = (_Float16)x1.w;
        #pragma unroll
        for (int ot = 0; ot < 4; ++ot) {
            f32x4 D;
            #pragma unroll
            for (int r = 0; r < 4; ++r) D[r] = nbv[ot];
            D = MFMA16(a, bN[ot], D);
            #pragma unroll
            for (int r = 0; r < 4; ++r) {
                int row = lg * 4 + r;
                sb[w][ti][swz(row, ot * 16 + lr)] = (_Float16)D[r];
            }
        }
        #pragma unroll
        for (int i = 0; i < 2; ++i) {
            int s = i * 64 + l, r = s >> 3, j = s & 7;
            f16x8 v = *(const f16x8*)&sb[w][ti][swz(r, j * 8)];
            *(f16x8*)&hOut[(size_t)nb * 64 + s * 8] = v;
        }
        f16x8 a0 = *(const f16x8*)&sb[w][ti][swz(lr, lg * 8)];
        f16x8 a1 = *(const f16x8*)&sb[w][ti][swz(lr, 32 + lg * 8)];
        #pragma unroll
        for (int ot = 0; ot < 4; ++ot) {
            f32x4 D;
            #pragma unroll
            for (int r = 0; r < 4; ++r) D[r] = 0.f;
            D = MFMA16(a0, bH[ot * 2 + 0], D);
            D = MFMA16(a1, bH[ot * 2 + 1], D);
            #pragma unroll
            for (int r = 0; r < 4; ++r) {
                int row = lg * 4 + r;
                sb[w][ti][swz(row, ot * 16 + lr)] = (_Float16)D[r];
            }
        }
        #pragma unroll
        for (int i = 0; i < 2; ++i) {
            int s = i * 64 + l, r = s >> 3, j = s & 7;
            f16x8 v = *(const f16x8*)&sb[w][ti][swz(r, j * 8)];
            *(f16x8*)&hWhOut[(size_t)nb * 64 + s * 8] = v;
        }
    }
}

// ---------------- MFMA fused node update (per layer) ----------------
__global__ __launch_bounds__(256)
void node_mfma_kernel(const _Float16* __restrict__ hIn, const float* __restrict__ aggZ,
                      const int* __restrict__ deg,
                      const _Float16* __restrict__ wE2, const _Float16* __restrict__ wU1a,
                      const _Float16* __restrict__ wU1b, const _Float16* __restrict__ wU2,
                      const _Float16* __restrict__ wNext,
                      const float* __restrict__ emb2, const float* __restrict__ umb1,
                      const float* __restrict__ umb2,
                      _Float16* __restrict__ hOut, _Float16* __restrict__ hWhOut)
{
    __shared__ _Float16 sb[4][NCH][16 * 64];
    int l = threadIdx.x & 63, w = threadIdx.x >> 6;
    int gid = blockIdx.x * 4 + w;
    if (gid >= NGROUPS) return;
    int lr = l & 15, lg = l >> 4;
    float eb2v[4], ub1v[4], ub2v[4];
    #pragma unroll
    for (int ot = 0; ot < 4; ++ot) {
        eb2v[ot] = emb2[ot * 16 + lr];
        ub1v[ot] = umb1[ot * 16 + lr];
        ub2v[ot] = umb2[ot * 16 + lr];
    }
    int t0 = gid * NCH;

    {   // stage A
        f16x8 bf[8];
        #pragma unroll
        for (int ot = 0; ot < 4; ++ot)
            #pragma unroll
            for (int kt = 0; kt < 2; ++kt)
                bf[ot * 2 + kt] = *(const f16x8*)&wE2[(ot * 16 + lr) * 64 + kt * 32 + lg * 8];
        for (int ti = 0; ti < NCH; ++ti) {
            int nb = (t0 + ti) * 16;
            const float* zs = aggZ + (size_t)(nb + lr) * 64 + lg * 8;
            float4 z0 = *(const float4*)zs;
            float4 z1 = *(const float4*)(zs + 4);
            float4 z2 = *(const float4*)(zs + 32);
            float4 z3 = *(const float4*)(zs + 36);
            f16x8 a0, a1;
            a0[0] = (_Float16)z0.x; a0[1] = (_Float16)z0.y; a0[2] = (_Float16)z0.z; a0[3] = (_Float16)z0.w;
            a0[4] = (_Float16)z1.x; a0[5] = (_Float16)z1.y; a0[6] = (_Float16)z1.z; a0[7] = (_Float16)z1.w;
            a1[0] = (_Float16)z2.x; a1[1] = (_Float16)z2.y; a1[2] = (_Float16)z2.z; a1[3] = (_Float16)z2.w;
            a1[4] = (_Float16)z3.x; a1[5] = (_Float16)z3.y; a1[6] = (_Float16)z3.z; a1[7] = (_Float16)z3.w;
            float dg[4];
            #pragma unroll
            for (int r = 0; r < 4; ++r) dg[r] = (float)deg[nb + lg * 4 + r];
            #pragma unroll
            for (int ot = 0; ot < 4; ++ot) {
                f32x4 D;
                #pragma unroll
                for (int r = 0; r < 4; ++r) D[r] = dg[r] * eb2v[ot];
                D = MFMA16(a0, bf[ot * 2 + 0], D);
                D = MFMA16(a1, bf[ot * 2 + 1], D);
                #pragma unroll
                for (int r = 0; r < 4; ++r) {
                    int row = lg * 4 + r;
                    sb[w][ti][swz(row, ot * 16 + lr)] = (_Float16)D[r];
                }
            }
        }
    }
    {   // stage T
        f16x8 bf[16];
        #pragma unroll
        for (int ot = 0; ot < 4; ++ot)
            #pragma unroll
            for (int kt = 0; kt < 2; ++kt) {
                bf[ot * 2 + kt]     = *(const f16x8*)&wU1a[(ot * 16 + lr) * 64 + kt * 32 + lg * 8];
                bf[8 + ot * 2 + kt] = *(const f16x8*)&wU1b[(ot * 16 + lr) * 64 + kt * 32 + lg * 8];
            }
        for (int ti = 0; ti < NCH; ++ti) {
            int nb = (t0 + ti) * 16;
            const _Float16* hs = hIn + (size_t)(nb + lr) * 64 + lg * 8;
            f16x8 a0 = *(const f16x8*)hs;
            f16x8 a1 = *(const f16x8*)(hs + 32);
            f16x8 c0 = *(const f16x8*)&sb[w][ti][swz(lr, lg * 8)];
            f16x8 c1 = *(const f16x8*)&sb[w][ti][swz(lr, 32 + lg * 8)];
            #pragma unroll
            for (int ot = 0; ot < 4; ++ot) {
                f32x4 D;
                #pragma unroll
                for (int r = 0; r < 4; ++r) D[r] = ub1v[ot];
                D = MFMA16(a0, bf[ot * 2 + 0], D);
                D = MFMA16(a1, bf[ot * 2 + 1], D);
                D = MFMA16(c0, bf[8 + ot * 2 + 0], D);
                D = MFMA16(c1, bf[8 + ot * 2 + 1], D);
                #pragma unroll
                for (int r = 0; r < 4; ++r) {
                    int row = lg * 4 + r;
                    sb[w][ti][swz(row, ot * 16 + lr)] = (_Float16)fmaxf(D[r], 0.f);
                }
            }
        }
    }
    {   // stage h'
        f16x8 bf[8];
        #pragma unroll
        for (int ot = 0; ot < 4; ++ot)
            #pragma unroll
            for (int kt = 0; kt < 2; ++kt)
                bf[ot * 2 + kt] = *(const f16x8*)&wU2[(ot * 16 + lr) * 64 + kt * 32 + lg * 8];
        for (int ti = 0; ti < NCH; ++ti) {
            int nb = (t0 + ti) * 16;
            f16x8 a0 = *(const f16x8*)&sb[w][ti][swz(lr, lg * 8)];
            f16x8 a1 = *(const f16x8*)&sb[w][ti][swz(lr, 32 + lg * 8)];
            #pragma unroll
            for (int ot = 0; ot < 4; ++ot) {
                f32x4 D;
                #pragma unroll
                for (int r = 0; r < 4; ++r) D[r] = ub2v[ot];
                D = MFMA16(a0, bf[ot * 2 + 0], D);
                D = MFMA16(a1, bf[ot * 2 + 1], D);
                #pragma unroll
                for (int r = 0; r < 4; ++r) {
                    int row = lg * 4 + r;
                    sb[w][ti][swz(row, ot * 16 + lr)] = (_Float16)D[r];
                }
            }
            #pragma unroll
            for (int i = 0; i < 2; ++i) {
                int s = i * 64 + l, r = s >> 3, j = s & 7;
                f16x8 v = *(const f16x8*)&sb[w][ti][swz(r, j * 8)];
                *(f16x8*)&hOut[(size_t)nb * 64 + s * 8] = v;
            }
        }
    }
    if (wNext) {   // stage hw
        f16x8 bf[8];
        #pragma unroll
        for (int ot = 0; ot < 4; ++ot)
            #pragma unroll
            for (int kt = 0; kt < 2; ++kt)
                bf[ot * 2 + kt] = *(const f16x8*)&wNext[(ot * 16 + lr) * 64 + kt * 32 + lg * 8];
        for (int ti = 0; ti < NCH; ++ti) {
            int nb = (t0 + ti) * 16;
            f16x8 a0 = *(const f16x8*)&sb[w][ti][swz(lr, lg * 8)];
            f16x8 a1 = *(const f16x8*)&sb[w][ti][swz(lr, 32 + lg * 8)];
            #pragma unroll
            for (int ot = 0; ot < 4; ++ot) {
                f32x4 D;
                #pragma unroll
                for (int r = 0; r < 4; ++r) D[r] = 0.f;
                D = MFMA16(a0, bf[ot * 2 + 0], D);
                D = MFMA16(a1, bf[ot * 2 + 1], D);
                #pragma unroll
                for (int r = 0; r < 4; ++r) {
                    int row = lg * 4 + r;
                    sb[w][ti][swz(row, ot * 16 + lr)] = (_Float16)D[r];
                }
            }
            #pragma unroll
            for (int i = 0; i < 2; ++i) {
                int s = i * 64 + l, r = s >> 3, j = s & 7;
                f16x8 v = *(const f16x8*)&sb[w][ti][swz(r, j * 8)];
                *(f16x8*)&hWhOut[(size_t)nb * 64 + s * 8] = v;
            }
        }
    }
}

// ---------------- edge aggregation (CSR gather, fp16, no atomics) ----------------
__device__ __forceinline__ float edge_term(float hv, uint4 a, uint4 b,
                                           const float* Kc, float kbo)
{
    float z = hv + kbo;
    float2 t;
    t = h2f2(a.x); z = fmaf(t.x, Kc[0], z);  z = fmaf(t.y, Kc[1], z);
    t = h2f2(a.y); z = fmaf(t.x, Kc[2], z);  z = fmaf(t.y, Kc[3], z);
    t = h2f2(a.z); z = fmaf(t.x, Kc[4], z);  z = fmaf(t.y, Kc[5], z);
    t = h2f2(a.w); z = fmaf(t.x, Kc[6], z);  z = fmaf(t.y, Kc[7], z);
    t = h2f2(b.x); z = fmaf(t.x, Kc[8], z);  z = fmaf(t.y, Kc[9], z);
    t = h2f2(b.y); z = fmaf(t.x, Kc[10], z); z = fmaf(t.y, Kc[11], z);
    t = h2f2(b.z); z = fmaf(t.x, Kc[12], z); z = fmaf(t.y, Kc[13], z);
    t = h2f2(b.w); z = fmaf(t.x, Kc[14], z); z = fmaf(t.y, Kc[15], z);
    return fmaxf(z, 0.f);
}

__global__ void edge_agg_kernel(const int* __restrict__ rowptr, const int* __restrict__ srcIdx,
                                const uint4* __restrict__ eaPh, const __half* __restrict__ hWh,
                                const float* __restrict__ K, const float* __restrict__ kb,
                                float* __restrict__ aggZ)
{
    int o = threadIdx.x & 63;
    int w = threadIdx.x >> 6;
    float Kc[EDGE_C];
    #pragma unroll
    for (int k = 0; k < EDGE_C; ++k) Kc[k] = K[k * HDIM + o];
    float kbo = kb[o];
    int wid = blockIdx.x * 4 + w, nw = gridDim.x * 4;
    for (int n = wid; n < N_NODES; n += nw) {
        int beg = __builtin_amdgcn_readfirstlane(rowptr[n]);
        int end = __builtin_amdgcn_readfirstlane(rowptr[n + 1]);
        float acc = 0.f;
        int p = beg;
        for (; p + 3 < end; p += 4) {
            int s0 = srcIdx[p], s1 = srcIdx[p + 1], s2 = srcIdx[p + 2], s3 = srcIdx[p + 3];
            uint4 a0 = eaPh[2 * (size_t)p + 0], b0 = eaPh[2 * (size_t)p + 1];
            uint4 a1 = eaPh[2 * (size_t)p + 2], b1 = eaPh[2 * (size_t)p + 3];
            uint4 a2 = eaPh[2 * (size_t)p + 4], b2 = eaPh[2 * (size_t)p + 5];
            uint4 a3 = eaPh[2 * (size_t)p + 6], b3 = eaPh[2 * (size_t)p + 7];
            float h0 = __half2float(hWh[(size_t)s0 * HDIM + o]);
            float h1 = __half2float(hWh[(size_t)s1 * HDIM + o]);
            float h2 = __half2float(hWh[(size_t)s2 * HDIM + o]);
            float h3 = __half2float(hWh[(size_t)s3 * HDIM + o]);
            acc += edge_term(h0, a0, b0, Kc, kbo);
            acc += edge_term(h1, a1, b1, Kc, kbo);
            acc += edge_term(h2, a2, b2, Kc, kbo);
            acc += edge_term(h3, a3, b3, Kc, kbo);
        }
        for (; p < end; ++p) {
            int s = srcIdx[p];
            uint4 a = eaPh[2 * (size_t)p], b = eaPh[2 * (size_t)p + 1];
            float hv = __half2float(hWh[(size_t)s * HDIM + o]);
            acc += edge_term(hv, a, b, Kc, kbo);
        }
        aggZ[(size_t)n * HDIM + o] = acc;
    }
}

// ---------------- pooling / readout ----------------
__global__ void pool_graph_kernel(const _Float16* __restrict__ h, const int* __restrict__ gptr,
                                  float* __restrict__ pooled)
{
    int o = threadIdx.x & 63;
    int w = threadIdx.x >> 6;
    int wid = blockIdx.x * 4 + w, nw = gridDim.x * 4;
    for (int g = wid; g < N_GRAPH; g += nw) {
        int beg = gptr[g], end = gptr[g + 1];
        float acc = 0.f;
        for (int n = beg; n < end; ++n) acc += (float)h[(size_t)n * HDIM + o];
        pooled[g * HDIM + o] = acc;
    }
}

__global__ void readout_kernel(const float* __restrict__ pooled, const int* __restrict__ gptr,
                               const float* __restrict__ desc,
                               const float* __restrict__ W1, const float* __restrict__ b1,
                               const float* __restrict__ W2, const float* __restrict__ b2,
                               float* __restrict__ out)
{
    __shared__ float r[HDIM + DESC_C];
    __shared__ float red[128];
    int g = blockIdx.x;
    int t = threadIdx.x;
    float c = fmaxf((float)(gptr[g + 1] - gptr[g]), 1.f);
    for (int i = t; i < HDIM; i += 128) r[i] = pooled[g * HDIM + i] / c;
    for (int i = t; i < DESC_C; i += 128) r[HDIM + i] = desc[(size_t)g * DESC_C + i];
    __syncthreads();
    float acc = b1[t];
    for (int k = 0; k < HDIM + DESC_C; ++k) acc = fmaf(r[k], W1[k * 128 + t], acc);
    acc = fmaxf(acc, 0.f) * W2[t];
    red[t] = acc;
    __syncthreads();
    for (int s = 64; s > 0; s >>= 1) {
        if (t < s) red[t] += red[t + s];
        __syncthreads();
    }
    if (t == 0) out[g] = 1.f / (1.f + expf(-(red[0] + b2[0])));
}

extern "C" void kernel_launch(void* const* d_in, const int* in_sizes, int n_in,
                              void* d_out, int out_size, void* d_ws, size_t ws_size,
                              hipStream_t stream)
{
    const float* x         = (const float*)d_in[0];
    const int*   ei        = (const int*)d_in[1];
    const float* edge_attr = (const float*)d_in[2];
    const int*   batch     = (const int*)d_in[3];
    const float* desc      = (const float*)d_in[4];
    const float* node_W    = (const float*)d_in[5];
    const float* node_b    = (const float*)d_in[6];
    const float* edge_W    = (const float*)d_in[7];
    const float* edge_b    = (const float*)d_in[8];
    const float* emW1      = (const float*)d_in[9];
    const float* emb1      = (const float*)d_in[10];
    const float* emW2      = (const float*)d_in[11];
    const float* emb2      = (const float*)d_in[12];
    const float* umW1      = (const float*)d_in[13];
    const float* umb1      = (const float*)d_in[14];
    const float* umW2      = (const float*)d_in[15];
    const float* umb2      = (const float*)d_in[16];
    const float* ro_W1     = (const float*)d_in[17];
    const float* ro_b1     = (const float*)d_in[18];
    const float* ro_W2     = (const float*)d_in[19];
    const float* ro_b2     = (const float*)d_in[20];

    size_t NH = (size_t)N_NODES * HDIM;
    char* base = (char*)d_ws;
    _Float16* hH   = (_Float16*)base;                        // 12.8 MB
    _Float16* hWh  = hH + NH;                                // 12.8 MB
    float* aggZ    = (float*)(base + NH * 4);                // 25.6 MB
    uint4* eaPh    = (uint4*)(base + NH * 8);                // 51.2 MB
    int2* stage    = (int2*)(eaPh + 2 * (size_t)N_EDGES);    // 12.8 MB
    int* srcIdx    = (int*)(stage + N_EDGES);                // 6.4 MB
    int* eIdx      = srcIdx + N_EDGES;                       // 6.4 MB
    int* bucketCnt = eIdx + N_EDGES;
    int* bucketBase= bucketCnt + NBUCK;
    int* bucketCur = bucketBase + NBUCK;
    int* rowptr    = bucketCur + NBUCK;
    int* deg       = rowptr + N_NODES + 1;
    int* gptr      = deg + N_NODES;
    float* K3      = (float*)(gptr + N_GRAPH + 1);
    float* kb3     = K3 + LAYERS * EDGE_C * HDIM;
    float* pooled  = kb3 + LAYERS * HDIM;
    _Float16* wt   = (_Float16*)(pooled + N_GRAPH * HDIM);

    hipMemsetAsync(bucketCnt, 0, NBUCK * sizeof(int), stream);

    wtcvt_kernel<<<256, 256, 0, stream>>>(node_W, emW1, emW2, umW1, umW2, wt);
    precompute_kernel<<<12, 256, 0, stream>>>(edge_W, edge_b, emW1, emb1, K3, kb3);

    // bucket-binned CSR build (no global write amplification)
    binA_count<<<GRID_A, 256, 0, stream>>>(ei, bucketCnt);
    binA_scan<<<1, 512, 0, stream>>>(bucketCnt, bucketBase, bucketCur);
    binA_scatter<<<GRID_A, 256, 0, stream>>>(ei, bucketCur, stage);
    binB_finalize<<<NBUCK, 256, 0, stream>>>(bucketCnt, bucketBase, stage,
                                             rowptr, deg, srcIdx, eIdx);
    perm_kernel<<<(N_EDGES + 255) / 256, 256, 0, stream>>>(eIdx, edge_attr, eaPh);
    gptr_kernel<<<(N_NODES + 255) / 256, 256, 0, stream>>>(batch, gptr);

    embed_mfma_kernel<<<NBLK, 256, 0, stream>>>(x, wt, node_b,
                                                wt + (size_t)1 * 4096, hH, hWh);

    for (int l = 0; l < LAYERS; ++l) {
        edge_agg_kernel<<<4096, 256, 0, stream>>>(rowptr, srcIdx, eaPh, (const __half*)hWh,
                                                  K3 + l * EDGE_C * HDIM, kb3 + l * HDIM, aggZ);
        const _Float16* wE2  = wt + (size_t)(1 + l * 5 + 1) * 4096;
        const _Float16* wU1a = wt + (size_t)(1 + l * 5 + 2) * 4096;
        const _Float16* wU1b = wt + (size_t)(1 + l * 5 + 3) * 4096;
        const _Float16* wU2  = wt + (size_t)(1 + l * 5 + 4) * 4096;
        const _Float16* wNx  = (l + 1 < LAYERS) ? (wt + (size_t)(1 + (l + 1) * 5 + 0) * 4096)
                                                : nullptr;
        node_mfma_kernel<<<NBLK, 256, 0, stream>>>(hH, aggZ, deg, wE2, wU1a, wU1b, wU2, wNx,
                                                   emb2 + l * HDIM, umb1 + l * HDIM,
                                                   umb2 + l * HDIM, hH, hWh);
    }

    pool_graph_kernel<<<256, 256, 0, stream>>>(hH, gptr, pooled);
    readout_kernel<<<N_GRAPH, 128, 0, stream>>>(pooled, gptr, desc, ro_W1, ro_b1, ro_W2, ro_b2,
                                                (float*)d_out);
}

// Round 11
// 641.906 us; speedup vs baseline: 1.3949x; 1.0596x over previous
//
#include <hip/hip_runtime.h>
#include <hip/hip_fp16.h>
#include <math.h>

#define N_NODES 100000
#define N_EDGES 1600000
#define N_GRAPH 1000
#define IN_C 32
#define EDGE_C 16
#define DESC_C 200
#define HDIM 64
#define LAYERS 3
#define NTILES (N_NODES / 16)
#define NCH 2
#define NGROUPS (NTILES / NCH)
#define NBLK ((NGROUPS + 3) / 4)

#define BUCK_SH 8
#define NBUCK ((N_NODES + 255) / 256)   // 391
#define EPB 4096
#define GRID_A ((N_EDGES + EPB - 1) / EPB)  // 391

using f16x8 = __attribute__((ext_vector_type(8))) _Float16;
using f32x4 = __attribute__((ext_vector_type(4))) float;
using v2h   = __attribute__((ext_vector_type(2))) _Float16;

#define MFMA16(a, b, c) __builtin_amdgcn_mfma_f32_16x16x32_f16((a), (b), (c), 0, 0, 0)

// ---------------- helpers ----------------
__device__ __forceinline__ unsigned int f2h2(float a, float b) {
    __half2 h = __floats2half2_rn(a, b);
    return *reinterpret_cast<unsigned int*>(&h);
}
__device__ __forceinline__ v2h as_v2h(unsigned int u) {
    union { unsigned int u; v2h h; } c; c.u = u; return c.h;
}
__device__ __forceinline__ int swz(int row, int c) {
    return row * 64 + (c ^ ((row & 7) << 3));
}

// ---------------- weight folding for edge kernel: K3h fp16-packed ----------------
// K3h[l][j][o] = half2( sum_t eW[2j][t]*W1l[t][o] , sum_t eW[2j+1][t]*W1l[t][o] )
__global__ void precompute_kernel(const float* __restrict__ edge_W, const float* __restrict__ edge_b,
                                  const float* __restrict__ emW1, const float* __restrict__ emb1,
                                  unsigned int* __restrict__ K3h, float* __restrict__ kb3)
{
    int tid = blockIdx.x * blockDim.x + threadIdx.x;
    if (tid < LAYERS * (EDGE_C / 2) * HDIM) {
        int l = tid / ((EDGE_C / 2) * HDIM);
        int j = (tid / HDIM) % (EDGE_C / 2);
        int o = tid % HDIM;
        const float* W1l = emW1 + l * (2 * HDIM * HDIM) + HDIM * HDIM;
        float a0 = 0.f, a1 = 0.f;
        for (int t = 0; t < HDIM; ++t) {
            float w = W1l[t * HDIM + o];
            a0 = fmaf(edge_W[(2 * j) * HDIM + t], w, a0);
            a1 = fmaf(edge_W[(2 * j + 1) * HDIM + t], w, a1);
        }
        K3h[tid] = f2h2(a0, a1);
    }
    if (tid < LAYERS * HDIM) {
        int l = tid / HDIM, o = tid % HDIM;
        const float* W1l = emW1 + l * (2 * HDIM * HDIM) + HDIM * HDIM;
        float acc = emb1[tid];
        for (int t = 0; t < HDIM; ++t)
            acc = fmaf(edge_b[t], W1l[t * HDIM + o], acc);
        kb3[tid] = acc;
    }
}

// ---------------- fp16 transposed weight prep ----------------
__global__ void wtcvt_kernel(const float* __restrict__ node_W, const float* __restrict__ emW1,
                             const float* __restrict__ emW2, const float* __restrict__ umW1,
                             const float* __restrict__ umW2, _Float16* __restrict__ wt)
{
    int tid = blockIdx.x * blockDim.x + threadIdx.x;
    if (tid >= 16 * 4096) return;
    int slot = tid >> 12, idx = tid & 4095;
    if (slot == 0) {
        if (idx >= 2048) return;
        int o = idx >> 5, k = idx & 31;
        wt[idx] = (_Float16)node_W[k * HDIM + o];
        return;
    }
    int s = slot - 1, lay = s / 5, m = s % 5;
    int o = idx >> 6, k = idx & 63;
    float v;
    if (m == 0)      v = emW1[lay * 2 * HDIM * HDIM + k * HDIM + o];
    else if (m == 1) v = emW2[lay * HDIM * HDIM + k * HDIM + o];
    else if (m == 2) v = umW1[lay * 2 * HDIM * HDIM + k * HDIM + o];
    else if (m == 3) v = umW1[lay * 2 * HDIM * HDIM + (HDIM + k) * HDIM + o];
    else             v = umW2[lay * HDIM * HDIM + k * HDIM + o];
    wt[slot * 4096 + idx] = (_Float16)v;
}

// ---------------- bucket binning: A1 count ----------------
__global__ __launch_bounds__(256)
void binA_count(const int* __restrict__ ei, int* __restrict__ bucketCnt)
{
    __shared__ int hist[NBUCK];
    for (int i = threadIdx.x; i < NBUCK; i += 256) hist[i] = 0;
    __syncthreads();
    int blk = blockIdx.x;
    #pragma unroll
    for (int i = 0; i < 16; ++i) {
        int e = blk * EPB + i * 256 + threadIdx.x;
        if (e < N_EDGES) {
            int dst = ei[N_EDGES + e];
            atomicAdd(&hist[dst >> BUCK_SH], 1);
        }
    }
    __syncthreads();
    for (int i = threadIdx.x; i < NBUCK; i += 256)
        if (hist[i]) atomicAdd(&bucketCnt[i], hist[i]);
}

// ---------------- A2: scan bucket counts ----------------
__global__ void binA_scan(const int* __restrict__ bucketCnt, int* __restrict__ bucketBase,
                          int* __restrict__ bucketCursor)
{
    __shared__ int s[512];
    int v = (threadIdx.x < NBUCK) ? bucketCnt[threadIdx.x] : 0;
    s[threadIdx.x] = v;
    __syncthreads();
    for (int off = 1; off < 512; off <<= 1) {
        int t = (threadIdx.x >= off) ? s[threadIdx.x - off] : 0;
        __syncthreads();
        s[threadIdx.x] += t;
        __syncthreads();
    }
    if (threadIdx.x < NBUCK) {
        int ex = s[threadIdx.x] - v;
        bucketBase[threadIdx.x] = ex;
        bucketCursor[threadIdx.x] = ex;
    }
}

// ---------------- A3: clustered scatter into bucket-major staging ----------------
__global__ __launch_bounds__(256)
void binA_scatter(const int* __restrict__ ei, int* __restrict__ bucketCursor,
                  int2* __restrict__ stage)
{
    __shared__ int hist[NBUCK];
    __shared__ int sbase[NBUCK];
    for (int i = threadIdx.x; i < NBUCK; i += 256) hist[i] = 0;
    __syncthreads();
    int blk = blockIdx.x;
    int pk[16], rnk[16], bkt[16];
    #pragma unroll
    for (int i = 0; i < 16; ++i) {
        int e = blk * EPB + i * 256 + threadIdx.x;
        bkt[i] = -1;
        if (e < N_EDGES) {
            int dst = ei[N_EDGES + e];
            int src = ei[e];
            bkt[i] = dst >> BUCK_SH;
            pk[i] = src | ((dst & 255) << 20);
            rnk[i] = atomicAdd(&hist[bkt[i]], 1);
        }
    }
    __syncthreads();
    for (int i = threadIdx.x; i < NBUCK; i += 256)
        if (hist[i]) sbase[i] = atomicAdd(&bucketCursor[i], hist[i]);
    __syncthreads();
    #pragma unroll
    for (int i = 0; i < 16; ++i) {
        if (bkt[i] >= 0) {
            int e = blk * EPB + i * 256 + threadIdx.x;
            stage[sbase[bkt[i]] + rnk[i]] = make_int2(pk[i], e);
        }
    }
}

// ---------------- B: per-bucket CSR finalize ----------------
__global__ __launch_bounds__(256)
void binB_finalize(const int* __restrict__ bucketCnt, const int* __restrict__ bucketBase,
                   const int2* __restrict__ stage, int* __restrict__ rowptr,
                   int* __restrict__ deg, int* __restrict__ srcIdx, int* __restrict__ eIdx)
{
    __shared__ int hist[256];
    __shared__ int s[256];
    __shared__ int cur[256];
    int b = blockIdx.x;
    int base = bucketBase[b], cnt = bucketCnt[b];
    int n0 = b << BUCK_SH;
    int nn = min(256, N_NODES - n0);
    hist[threadIdx.x] = 0;
    __syncthreads();
    for (int j = threadIdx.x; j < cnt; j += 256)
        atomicAdd(&hist[(stage[base + j].x >> 20) & 255], 1);
    __syncthreads();
    int v = hist[threadIdx.x];
    s[threadIdx.x] = v;
    __syncthreads();
    for (int off = 1; off < 256; off <<= 1) {
        int t = (threadIdx.x >= off) ? s[threadIdx.x - off] : 0;
        __syncthreads();
        s[threadIdx.x] += t;
        __syncthreads();
    }
    int ex = s[threadIdx.x] - v;
    if (threadIdx.x < nn) {
        rowptr[n0 + threadIdx.x] = base + ex;
        deg[n0 + threadIdx.x] = v;
    }
    cur[threadIdx.x] = ex;
    if (b == 0 && threadIdx.x == 0) rowptr[N_NODES] = N_EDGES;
    __syncthreads();
    for (int j = threadIdx.x; j < cnt; j += 256) {
        int2 se = stage[base + j];
        int dl = (se.x >> 20) & 255;
        int r = atomicAdd(&cur[dl], 1);
        srcIdx[base + r] = se.x & 0x1FFFF;
        eIdx[base + r] = se.y;
    }
}

// ---------------- perm: gather fp32 edge_attr by CSR order, write fp16 ----------------
__global__ void perm_kernel(const int* __restrict__ eIdx, const float* __restrict__ ea,
                            uint4* __restrict__ eaPh)
{
    int pos = blockIdx.x * blockDim.x + threadIdx.x;
    if (pos < N_EDGES) {
        int e = eIdx[pos];
        const float4* er = reinterpret_cast<const float4*>(ea + (size_t)e * EDGE_C);
        float4 f0 = er[0], f1 = er[1], f2 = er[2], f3 = er[3];
        uint4 u0, u1;
        u0.x = f2h2(f0.x, f0.y);  u0.y = f2h2(f0.z, f0.w);
        u0.z = f2h2(f1.x, f1.y);  u0.w = f2h2(f1.z, f1.w);
        u1.x = f2h2(f2.x, f2.y);  u1.y = f2h2(f2.z, f2.w);
        u1.z = f2h2(f3.x, f3.y);  u1.w = f2h2(f3.z, f3.w);
        eaPh[2 * (size_t)pos]     = u0;
        eaPh[2 * (size_t)pos + 1] = u1;
    }
}

// ---------------- gptr from sorted batch ----------------
__global__ void gptr_kernel(const int* __restrict__ batch, int* __restrict__ gptr)
{
    int n = blockIdx.x * blockDim.x + threadIdx.x;
    if (n < N_NODES) {
        int b = batch[n];
        if (n == 0) {
            for (int g = 0; g <= b; ++g) gptr[g] = 0;
        } else {
            int pb = batch[n - 1];
            for (int g = pb + 1; g <= b; ++g) gptr[g] = n;
        }
        if (n == N_NODES - 1)
            for (int g = b + 1; g <= N_GRAPH; ++g) gptr[g] = N_NODES;
    }
}

// ---------------- MFMA embed ----------------
__global__ __launch_bounds__(256)
void embed_mfma_kernel(const float* __restrict__ x, const _Float16* __restrict__ wNt,
                       const float* __restrict__ node_b, const _Float16* __restrict__ wW1,
                       _Float16* __restrict__ hOut, _Float16* __restrict__ hWhOut)
{
    __shared__ _Float16 sb[4][NCH][16 * 64];
    int l = threadIdx.x & 63, w = threadIdx.x >> 6;
    int gid = blockIdx.x * 4 + w;
    if (gid >= NGROUPS) return;
    int lr = l & 15, lg = l >> 4;
    float nbv[4];
    #pragma unroll
    for (int ot = 0; ot < 4; ++ot) nbv[ot] = node_b[ot * 16 + lr];
    f16x8 bN[4];
    #pragma unroll
    for (int ot = 0; ot < 4; ++ot)
        bN[ot] = *(const f16x8*)&wNt[(ot * 16 + lr) * 32 + lg * 8];
    f16x8 bH[8];
    #pragma unroll
    for (int ot = 0; ot < 4; ++ot)
        #pragma unroll
        for (int kt = 0; kt < 2; ++kt)
            bH[ot * 2 + kt] = *(const f16x8*)&wW1[(ot * 16 + lr) * 64 + kt * 32 + lg * 8];

    for (int ti = 0; ti < NCH; ++ti) {
        int nb = (gid * NCH + ti) * 16;
        const float* xs = x + (size_t)(nb + lr) * IN_C + lg * 8;
        float4 x0 = *(const float4*)xs;
        float4 x1 = *(const float4*)(xs + 4);
        f16x8 a;
        a[0] = (_Float16)x0.x; a[1] = (_Float16)x0.y; a[2] = (_Float16)x0.z; a[3] = (_Float16)x0.w;
        a[4] = (_Float16)x1.x; a[5] = (_Float16)x1.y; a[6] = (_Float16)x1.z; a[7] = (_Float16)x1.w;
        #pragma unroll
        for (int ot = 0; ot < 4; ++ot) {
            f32x4 D;
            #pragma unroll
            for (int r = 0; r < 4; ++r) D[r] = nbv[ot];
            D = MFMA16(a, bN[ot], D);
            #pragma unroll
            for (int r = 0; r < 4; ++r) {
                int row = lg * 4 + r;
                sb[w][ti][swz(row, ot * 16 + lr)] = (_Float16)D[r];
            }
        }
        #pragma unroll
        for (int i = 0; i < 2; ++i) {
            int s = i * 64 + l, r = s >> 3, j = s & 7;
            f16x8 v = *(const f16x8*)&sb[w][ti][swz(r, j * 8)];
            *(f16x8*)&hOut[(size_t)nb * 64 + s * 8] = v;
        }
        f16x8 a0 = *(const f16x8*)&sb[w][ti][swz(lr, lg * 8)];
        f16x8 a1 = *(const f16x8*)&sb[w][ti][swz(lr, 32 + lg * 8)];
        #pragma unroll
        for (int ot = 0; ot < 4; ++ot) {
            f32x4 D;
            #pragma unroll
            for (int r = 0; r < 4; ++r) D[r] = 0.f;
            D = MFMA16(a0, bH[ot * 2 + 0], D);
            D = MFMA16(a1, bH[ot * 2 + 1], D);
            #pragma unroll
            for (int r = 0; r < 4; ++r) {
                int row = lg * 4 + r;
                sb[w][ti][swz(row, ot * 16 + lr)] = (_Float16)D[r];
            }
        }
        #pragma unroll
        for (int i = 0; i < 2; ++i) {
            int s = i * 64 + l, r = s >> 3, j = s & 7;
            f16x8 v = *(const f16x8*)&sb[w][ti][swz(r, j * 8)];
            *(f16x8*)&hWhOut[(size_t)nb * 64 + s * 8] = v;
        }
    }
}

// ---------------- MFMA fused node update (per layer) ----------------
__global__ __launch_bounds__(256)
void node_mfma_kernel(const _Float16* __restrict__ hIn, const float* __restrict__ aggZ,
                      const int* __restrict__ deg,
                      const _Float16* __restrict__ wE2, const _Float16* __restrict__ wU1a,
                      const _Float16* __restrict__ wU1b, const _Float16* __restrict__ wU2,
                      const _Float16* __restrict__ wNext,
                      const float* __restrict__ emb2, const float* __restrict__ umb1,
                      const float* __restrict__ umb2,
                      _Float16* __restrict__ hOut, _Float16* __restrict__ hWhOut)
{
    __shared__ _Float16 sb[4][NCH][16 * 64];
    int l = threadIdx.x & 63, w = threadIdx.x >> 6;
    int gid = blockIdx.x * 4 + w;
    if (gid >= NGROUPS) return;
    int lr = l & 15, lg = l >> 4;
    float eb2v[4], ub1v[4], ub2v[4];
    #pragma unroll
    for (int ot = 0; ot < 4; ++ot) {
        eb2v[ot] = emb2[ot * 16 + lr];
        ub1v[ot] = umb1[ot * 16 + lr];
        ub2v[ot] = umb2[ot * 16 + lr];
    }
    int t0 = gid * NCH;

    {   // stage A
        f16x8 bf[8];
        #pragma unroll
        for (int ot = 0; ot < 4; ++ot)
            #pragma unroll
            for (int kt = 0; kt < 2; ++kt)
                bf[ot * 2 + kt] = *(const f16x8*)&wE2[(ot * 16 + lr) * 64 + kt * 32 + lg * 8];
        for (int ti = 0; ti < NCH; ++ti) {
            int nb = (t0 + ti) * 16;
            const float* zs = aggZ + (size_t)(nb + lr) * 64 + lg * 8;
            float4 z0 = *(const float4*)zs;
            float4 z1 = *(const float4*)(zs + 4);
            float4 z2 = *(const float4*)(zs + 32);
            float4 z3 = *(const float4*)(zs + 36);
            f16x8 a0, a1;
            a0[0] = (_Float16)z0.x; a0[1] = (_Float16)z0.y; a0[2] = (_Float16)z0.z; a0[3] = (_Float16)z0.w;
            a0[4] = (_Float16)z1.x; a0[5] = (_Float16)z1.y; a0[6] = (_Float16)z1.z; a0[7] = (_Float16)z1.w;
            a1[0] = (_Float16)z2.x; a1[1] = (_Float16)z2.y; a1[2] = (_Float16)z2.z; a1[3] = (_Float16)z2.w;
            a1[4] = (_Float16)z3.x; a1[5] = (_Float16)z3.y; a1[6] = (_Float16)z3.z; a1[7] = (_Float16)z3.w;
            float dg[4];
            #pragma unroll
            for (int r = 0; r < 4; ++r) dg[r] = (float)deg[nb + lg * 4 + r];
            #pragma unroll
            for (int ot = 0; ot < 4; ++ot) {
                f32x4 D;
                #pragma unroll
                for (int r = 0; r < 4; ++r) D[r] = dg[r] * eb2v[ot];
                D = MFMA16(a0, bf[ot * 2 + 0], D);
                D = MFMA16(a1, bf[ot * 2 + 1], D);
                #pragma unroll
                for (int r = 0; r < 4; ++r) {
                    int row = lg * 4 + r;
                    sb[w][ti][swz(row, ot * 16 + lr)] = (_Float16)D[r];
                }
            }
        }
    }
    {   // stage T
        f16x8 bf[16];
        #pragma unroll
        for (int ot = 0; ot < 4; ++ot)
            #pragma unroll
            for (int kt = 0; kt < 2; ++kt) {
                bf[ot * 2 + kt]     = *(const f16x8*)&wU1a[(ot * 16 + lr) * 64 + kt * 32 + lg * 8];
                bf[8 + ot * 2 + kt] = *(const f16x8*)&wU1b[(ot * 16 + lr) * 64 + kt * 32 + lg * 8];
            }
        for (int ti = 0; ti < NCH; ++ti) {
            int nb = (t0 + ti) * 16;
            const _Float16* hs = hIn + (size_t)(nb + lr) * 64 + lg * 8;
            f16x8 a0 = *(const f16x8*)hs;
            f16x8 a1 = *(const f16x8*)(hs + 32);
            f16x8 c0 = *(const f16x8*)&sb[w][ti][swz(lr, lg * 8)];
            f16x8 c1 = *(const f16x8*)&sb[w][ti][swz(lr, 32 + lg * 8)];
            #pragma unroll
            for (int ot = 0; ot < 4; ++ot) {
                f32x4 D;
                #pragma unroll
                for (int r = 0; r < 4; ++r) D[r] = ub1v[ot];
                D = MFMA16(a0, bf[ot * 2 + 0], D);
                D = MFMA16(a1, bf[ot * 2 + 1], D);
                D = MFMA16(c0, bf[8 + ot * 2 + 0], D);
                D = MFMA16(c1, bf[8 + ot * 2 + 1], D);
                #pragma unroll
                for (int r = 0; r < 4; ++r) {
                    int row = lg * 4 + r;
                    sb[w][ti][swz(row, ot * 16 + lr)] = (_Float16)fmaxf(D[r], 0.f);
                }
            }
        }
    }
    {   // stage h'
        f16x8 bf[8];
        #pragma unroll
        for (int ot = 0; ot < 4; ++ot)
            #pragma unroll
            for (int kt = 0; kt < 2; ++kt)
                bf[ot * 2 + kt] = *(const f16x8*)&wU2[(ot * 16 + lr) * 64 + kt * 32 + lg * 8];
        for (int ti = 0; ti < NCH; ++ti) {
            int nb = (t0 + ti) * 16;
            f16x8 a0 = *(const f16x8*)&sb[w][ti][swz(lr, lg * 8)];
            f16x8 a1 = *(const f16x8*)&sb[w][ti][swz(lr, 32 + lg * 8)];
            #pragma unroll
            for (int ot = 0; ot < 4; ++ot) {
                f32x4 D;
                #pragma unroll
                for (int r = 0; r < 4; ++r) D[r] = ub2v[ot];
                D = MFMA16(a0, bf[ot * 2 + 0], D);
                D = MFMA16(a1, bf[ot * 2 + 1], D);
                #pragma unroll
                for (int r = 0; r < 4; ++r) {
                    int row = lg * 4 + r;
                    sb[w][ti][swz(row, ot * 16 + lr)] = (_Float16)D[r];
                }
            }
            #pragma unroll
            for (int i = 0; i < 2; ++i) {
                int s = i * 64 + l, r = s >> 3, j = s & 7;
                f16x8 v = *(const f16x8*)&sb[w][ti][swz(r, j * 8)];
                *(f16x8*)&hOut[(size_t)nb * 64 + s * 8] = v;
            }
        }
    }
    if (wNext) {   // stage hw
        f16x8 bf[8];
        #pragma unroll
        for (int ot = 0; ot < 4; ++ot)
            #pragma unroll
            for (int kt = 0; kt < 2; ++kt)
                bf[ot * 2 + kt] = *(const f16x8*)&wNext[(ot * 16 + lr) * 64 + kt * 32 + lg * 8];
        for (int ti = 0; ti < NCH; ++ti) {
            int nb = (t0 + ti) * 16;
            f16x8 a0 = *(const f16x8*)&sb[w][ti][swz(lr, lg * 8)];
            f16x8 a1 = *(const f16x8*)&sb[w][ti][swz(lr, 32 + lg * 8)];
            #pragma unroll
            for (int ot = 0; ot < 4; ++ot) {
                f32x4 D;
                #pragma unroll
                for (int r = 0; r < 4; ++r) D[r] = 0.f;
                D = MFMA16(a0, bf[ot * 2 + 0], D);
                D = MFMA16(a1, bf[ot * 2 + 1], D);
                #pragma unroll
                for (int r = 0; r < 4; ++r) {
                    int row = lg * 4 + r;
                    sb[w][ti][swz(row, ot * 16 + lr)] = (_Float16)D[r];
                }
            }
            #pragma unroll
            for (int i = 0; i < 2; ++i) {
                int s = i * 64 + l, r = s >> 3, j = s & 7;
                f16x8 v = *(const f16x8*)&sb[w][ti][swz(r, j * 8)];
                *(f16x8*)&hWhOut[(size_t)nb * 64 + s * 8] = v;
            }
        }
    }
}

// ---------------- edge aggregation: v_dot2_f32_f16, no unpack cvts ----------------
__device__ __forceinline__ float edge_term(float base, uint4 a, uint4 b, const v2h* Kc)
{
    float z = base;
    z = __builtin_amdgcn_fdot2(as_v2h(a.x), Kc[0], z, false);
    z = __builtin_amdgcn_fdot2(as_v2h(a.y), Kc[1], z, false);
    z = __builtin_amdgcn_fdot2(as_v2h(a.z), Kc[2], z, false);
    z = __builtin_amdgcn_fdot2(as_v2h(a.w), Kc[3], z, false);
    z = __builtin_amdgcn_fdot2(as_v2h(b.x), Kc[4], z, false);
    z = __builtin_amdgcn_fdot2(as_v2h(b.y), Kc[5], z, false);
    z = __builtin_amdgcn_fdot2(as_v2h(b.z), Kc[6], z, false);
    z = __builtin_amdgcn_fdot2(as_v2h(b.w), Kc[7], z, false);
    return fmaxf(z, 0.f);
}

__global__ void edge_agg_kernel(const int* __restrict__ rowptr, const int* __restrict__ srcIdx,
                                const uint4* __restrict__ eaPh, const __half* __restrict__ hWh,
                                const unsigned int* __restrict__ K3h, const float* __restrict__ kb,
                                float* __restrict__ aggZ)
{
    int o = threadIdx.x & 63;
    int w = threadIdx.x >> 6;
    v2h Kc[EDGE_C / 2];
    #pragma unroll
    for (int j = 0; j < EDGE_C / 2; ++j) Kc[j] = as_v2h(K3h[j * HDIM + o]);
    float kbo = kb[o];
    int wid = blockIdx.x * 4 + w, nw = gridDim.x * 4;
    for (int n = wid; n < N_NODES; n += nw) {
        int beg = __builtin_amdgcn_readfirstlane(rowptr[n]);
        int end = __builtin_amdgcn_readfirstlane(rowptr[n + 1]);
        float acc = 0.f;
        int p = beg;
        for (; p + 3 < end; p += 4) {
            int s0 = srcIdx[p], s1 = srcIdx[p + 1], s2 = srcIdx[p + 2], s3 = srcIdx[p + 3];
            uint4 a0 = eaPh[2 * (size_t)p + 0], b0 = eaPh[2 * (size_t)p + 1];
            uint4 a1 = eaPh[2 * (size_t)p + 2], b1 = eaPh[2 * (size_t)p + 3];
            uint4 a2 = eaPh[2 * (size_t)p + 4], b2 = eaPh[2 * (size_t)p + 5];
            uint4 a3 = eaPh[2 * (size_t)p + 6], b3 = eaPh[2 * (size_t)p + 7];
            float h0 = __half2float(hWh[(size_t)s0 * HDIM + o]);
            float h1 = __half2float(hWh[(size_t)s1 * HDIM + o]);
            float h2 = __half2float(hWh[(size_t)s2 * HDIM + o]);
            float h3 = __half2float(hWh[(size_t)s3 * HDIM + o]);
            acc += edge_term(h0 + kbo, a0, b0, Kc);
            acc += edge_term(h1 + kbo, a1, b1, Kc);
            acc += edge_term(h2 + kbo, a2, b2, Kc);
            acc += edge_term(h3 + kbo, a3, b3, Kc);
        }
        for (; p < end; ++p) {
            int s = srcIdx[p];
            uint4 a = eaPh[2 * (size_t)p], b = eaPh[2 * (size_t)p + 1];
            float hv = __half2float(hWh[(size_t)s * HDIM + o]);
            acc += edge_term(hv + kbo, a, b, Kc);
        }
        aggZ[(size_t)n * HDIM + o] = acc;
    }
}

// ---------------- pooling / readout ----------------
__global__ void pool_graph_kernel(const _Float16* __restrict__ h, const int* __restrict__ gptr,
                                  float* __restrict__ pooled)
{
    int o = threadIdx.x & 63;
    int w = threadIdx.x >> 6;
    int wid = blockIdx.x * 4 + w, nw = gridDim.x * 4;
    for (int g = wid; g < N_GRAPH; g += nw) {
        int beg = gptr[g], end = gptr[g + 1];
        float acc = 0.f;
        for (int n = beg; n < end; ++n) acc += (float)h[(size_t)n * HDIM + o];
        pooled[g * HDIM + o] = acc;
    }
}

__global__ void readout_kernel(const float* __restrict__ pooled, const int* __restrict__ gptr,
                               const float* __restrict__ desc,
                               const float* __restrict__ W1, const float* __restrict__ b1,
                               const float* __restrict__ W2, const float* __restrict__ b2,
                               float* __restrict__ out)
{
    __shared__ float r[HDIM + DESC_C];
    __shared__ float red[128];
    int g = blockIdx.x;
    int t = threadIdx.x;
    float c = fmaxf((float)(gptr[g + 1] - gptr[g]), 1.f);
    for (int i = t; i < HDIM; i += 128) r[i] = pooled[g * HDIM + i] / c;
    for (int i = t; i < DESC_C; i += 128) r[HDIM + i] = desc[(size_t)g * DESC_C + i];
    __syncthreads();
    float acc = b1[t];
    for (int k = 0; k < HDIM + DESC_C; ++k) acc = fmaf(r[k], W1[k * 128 + t], acc);
    acc = fmaxf(acc, 0.f) * W2[t];
    red[t] = acc;
    __syncthreads();
    for (int s = 64; s > 0; s >>= 1) {
        if (t < s) red[t] += red[t + s];
        __syncthreads();
    }
    if (t == 0) out[g] = 1.f / (1.f + expf(-(red[0] + b2[0])));
}

extern "C" void kernel_launch(void* const* d_in, const int* in_sizes, int n_in,
                              void* d_out, int out_size, void* d_ws, size_t ws_size,
                              hipStream_t stream)
{
    const float* x         = (const float*)d_in[0];
    const int*   ei        = (const int*)d_in[1];
    const float* edge_attr = (const float*)d_in[2];
    const int*   batch     = (const int*)d_in[3];
    const float* desc      = (const float*)d_in[4];
    const float* node_W    = (const float*)d_in[5];
    const float* node_b    = (const float*)d_in[6];
    const float* edge_W    = (const float*)d_in[7];
    const float* edge_b    = (const float*)d_in[8];
    const float* emW1      = (const float*)d_in[9];
    const float* emb1      = (const float*)d_in[10];
    const float* emW2      = (const float*)d_in[11];
    const float* emb2      = (const float*)d_in[12];
    const float* umW1      = (const float*)d_in[13];
    const float* umb1      = (const float*)d_in[14];
    const float* umW2      = (const float*)d_in[15];
    const float* umb2      = (const float*)d_in[16];
    const float* ro_W1     = (const float*)d_in[17];
    const float* ro_b1     = (const float*)d_in[18];
    const float* ro_W2     = (const float*)d_in[19];
    const float* ro_b2     = (const float*)d_in[20];

    size_t NH = (size_t)N_NODES * HDIM;
    char* base = (char*)d_ws;
    _Float16* hH   = (_Float16*)base;                        // 12.8 MB
    _Float16* hWh  = hH + NH;                                // 12.8 MB
    float* aggZ    = (float*)(base + NH * 4);                // 25.6 MB
    uint4* eaPh    = (uint4*)(base + NH * 8);                // 51.2 MB
    int2* stage    = (int2*)(eaPh + 2 * (size_t)N_EDGES);    // 12.8 MB
    int* srcIdx    = (int*)(stage + N_EDGES);                // 6.4 MB
    int* eIdx      = srcIdx + N_EDGES;                       // 6.4 MB
    int* bucketCnt = eIdx + N_EDGES;
    int* bucketBase= bucketCnt + NBUCK;
    int* bucketCur = bucketBase + NBUCK;
    int* rowptr    = bucketCur + NBUCK;
    int* deg       = rowptr + N_NODES + 1;
    int* gptr      = deg + N_NODES;
    unsigned int* K3h = (unsigned int*)(gptr + N_GRAPH + 1);
    float* kb3     = (float*)(K3h + LAYERS * (EDGE_C / 2) * HDIM);
    float* pooled  = kb3 + LAYERS * HDIM;
    _Float16* wt   = (_Float16*)(pooled + N_GRAPH * HDIM);

    hipMemsetAsync(bucketCnt, 0, NBUCK * sizeof(int), stream);

    wtcvt_kernel<<<256, 256, 0, stream>>>(node_W, emW1, emW2, umW1, umW2, wt);
    precompute_kernel<<<6, 256, 0, stream>>>(edge_W, edge_b, emW1, emb1, K3h, kb3);

    // bucket-binned CSR build
    binA_count<<<GRID_A, 256, 0, stream>>>(ei, bucketCnt);
    binA_scan<<<1, 512, 0, stream>>>(bucketCnt, bucketBase, bucketCur);
    binA_scatter<<<GRID_A, 256, 0, stream>>>(ei, bucketCur, stage);
    binB_finalize<<<NBUCK, 256, 0, stream>>>(bucketCnt, bucketBase, stage,
                                             rowptr, deg, srcIdx, eIdx);
    perm_kernel<<<(N_EDGES + 255) / 256, 256, 0, stream>>>(eIdx, edge_attr, eaPh);
    gptr_kernel<<<(N_NODES + 255) / 256, 256, 0, stream>>>(batch, gptr);

    embed_mfma_kernel<<<NBLK, 256, 0, stream>>>(x, wt, node_b,
                                                wt + (size_t)1 * 4096, hH, hWh);

    for (int l = 0; l < LAYERS; ++l) {
        edge_agg_kernel<<<4096, 256, 0, stream>>>(rowptr, srcIdx, eaPh, (const __half*)hWh,
                                                  K3h + l * (EDGE_C / 2) * HDIM,
                                                  kb3 + l * HDIM, aggZ);
        const _Float16* wE2  = wt + (size_t)(1 + l * 5 + 1) * 4096;
        const _Float16* wU1a = wt + (size_t)(1 + l * 5 + 2) * 4096;
        const _Float16* wU1b = wt + (size_t)(1 + l * 5 + 3) * 4096;
        const _Float16* wU2  = wt + (size_t)(1 + l * 5 + 4) * 4096;
        const _Float16* wNx  = (l + 1 < LAYERS) ? (wt + (size_t)(1 + (l + 1) * 5 + 0) * 4096)
                                                : nullptr;
        node_mfma_kernel<<<NBLK, 256, 0, stream>>>(hH, aggZ, deg, wE2, wU1a, wU1b, wU2, wNx,
                                                   emb2 + l * HDIM, umb1 + l * HDIM,
                                                   umb2 + l * HDIM, hH, hWh);
    }

    pool_graph_kernel<<<256, 256, 0, stream>>>(hH, gptr, pooled);
    readout_kernel<<<N_GRAPH, 128, 0, stream>>>(pooled, gptr, desc, ro_W1, ro_b1, ro_W2, ro_b2,
                                                (float*)d_out);
}